// Round 2
// baseline (330.812 us; speedup 1.0000x reference)
//
#include <hip/hip_runtime.h>

// Problem constants (from reference)
#define BB 4096   // batch
#define NN 64     // neighbors
#define DD 128    // dim

__global__ __launch_bounds__(256) void fused_gather_softmax_agg(
    const int* __restrict__ data_r,        // [B,N] indices into edge_w
    const int* __restrict__ data_e,        // [B,N] indices into ent_emb
    const int* __restrict__ rel,           // [B]
    const int* __restrict__ pos_id,        // [B]
    const int* __restrict__ neg_id,        // [B]
    const float* __restrict__ ent_emb,     // [500001,128] f32
    const float* __restrict__ edge_w,      // [250501,1]   f32
    const float* __restrict__ rel_emb,     // [500,128]    f32
    float* __restrict__ out)               // [3*B*128]    f32
{
    const int wave = threadIdx.x >> 6;     // 4 waves per block, 1 batch row each
    const int lane = threadIdx.x & 63;
    const int b    = blockIdx.x * 4 + wave;

    // ---- 1. softmax over the 64 gathered edge weights (one per lane) ----
    const int ridx = data_r[b * NN + lane];
    const float wv = edge_w[ridx];

    float m = wv;
#pragma unroll
    for (int off = 32; off; off >>= 1) m = fmaxf(m, __shfl_xor(m, off));
    const float ex = __expf(wv - m);
    float s = ex;
#pragma unroll
    for (int off = 32; off; off >>= 1) s += __shfl_xor(s, off);
    const float w = ex / s;

    const int eidx = data_e[b * NN + lane];

    // ---- 2. weighted sum of 64 entity rows (512 B each) ----
    // 4 row-groups of 16 lanes; each group loads one full row per iter
    // (each lane: 2 adjacent float4 = 32 B, covering dims [8*sl, 8*sl+8)).
    const int rg = lane >> 4;    // 0..3 : which neighbor row this lane helps load
    const int sl = lane & 15;    // 0..15: owns dims [8*sl, 8*sl+8)

    float acc[8];
#pragma unroll
    for (int i = 0; i < 8; ++i) acc[i] = 0.f;

#pragma unroll 4
    for (int t = 0; t < 16; ++t) {
        const int   n   = t * 4 + rg;
        const int   idx = __shfl(eidx, n);
        const float wn  = __shfl(w, n);
        const float4* rp = (const float4*)(ent_emb + (size_t)idx * DD) + sl * 2;
        const float4 v0 = rp[0];
        const float4 v1 = rp[1];
        acc[0] = fmaf(wn, v0.x, acc[0]); acc[1] = fmaf(wn, v0.y, acc[1]);
        acc[2] = fmaf(wn, v0.z, acc[2]); acc[3] = fmaf(wn, v0.w, acc[3]);
        acc[4] = fmaf(wn, v1.x, acc[4]); acc[5] = fmaf(wn, v1.y, acc[5]);
        acc[6] = fmaf(wn, v1.z, acc[6]); acc[7] = fmaf(wn, v1.w, acc[7]);
    }

    // reduce partials across the 4 row-groups (lanes sl, sl+16, sl+32, sl+48)
#pragma unroll
    for (int i = 0; i < 8; ++i) {
        acc[i] += __shfl_xor(acc[i], 16);
        acc[i] += __shfl_xor(acc[i], 32);
    }

    // ---- 3. epilogue: rg0 -> out_t, rg1 -> pos_out, rg2 -> neg_out ----
    if (rg == 0) {
        const int r = rel[b];
        const float4* rv = (const float4*)(rel_emb + (size_t)r * DD) + sl * 2;
        const float4 r0 = rv[0];
        const float4 r1 = rv[1];
        float4 o0, o1;
        o0.x = acc[0] + r0.x; o0.y = acc[1] + r0.y;
        o0.z = acc[2] + r0.z; o0.w = acc[3] + r0.w;
        o1.x = acc[4] + r1.x; o1.y = acc[5] + r1.y;
        o1.z = acc[6] + r1.z; o1.w = acc[7] + r1.w;
        float4* op = (float4*)(out + (size_t)b * DD) + sl * 2;
        op[0] = o0;
        op[1] = o1;
    } else if (rg == 1) {
        const int p = pos_id[b];
        const float4* rp = (const float4*)(ent_emb + (size_t)p * DD) + sl * 2;
        float4* op = (float4*)(out + (size_t)BB * DD + (size_t)b * DD) + sl * 2;
        op[0] = rp[0];
        op[1] = rp[1];
    } else if (rg == 2) {
        const int ng = neg_id[b];
        const float4* rp = (const float4*)(ent_emb + (size_t)ng * DD) + sl * 2;
        float4* op = (float4*)(out + (size_t)2 * BB * DD + (size_t)b * DD) + sl * 2;
        op[0] = rp[0];
        op[1] = rp[1];
    }
}

extern "C" void kernel_launch(void* const* d_in, const int* in_sizes, int n_in,
                              void* d_out, int out_size, void* d_ws, size_t ws_size,
                              hipStream_t stream) {
    const int* data_r = (const int*)d_in[0];
    const int* data_e = (const int*)d_in[1];
    const int* rel    = (const int*)d_in[2];
    const int* pos_id = (const int*)d_in[3];
    const int* neg_id = (const int*)d_in[4];
    const float* ent_emb = (const float*)d_in[5];
    const float* edge_w  = (const float*)d_in[6];
    const float* rel_emb = (const float*)d_in[7];
    float* out = (float*)d_out;

    dim3 grid(BB / 4);   // 4 batch rows per 256-thread block
    dim3 block(256);
    fused_gather_softmax_agg<<<grid, block, 0, stream>>>(
        data_r, data_e, rel, pos_id, neg_id, ent_emb, edge_w, rel_emb, out);
}

// Round 3
// 329.557 us; speedup vs baseline: 1.0038x; 1.0038x over previous
//
#include <hip/hip_runtime.h>

// Problem constants (from reference)
#define BB 4096   // batch
#define NN 64     // neighbors
#define DD 128    // dim

// One 256-thread block per batch row. Each of the 4 waves gathers 16 of the
// 64 neighbor rows (4 iterations x 4 row-groups of 16 lanes, 2x float4/lane,
// each load instruction = one contiguous 256B segment of a row). Partials are
// combined across waves through 2KB of LDS. Softmax over the 64 edge weights
// is computed redundantly per wave (edge_w is 1MB -> L2-resident; cheaper
// than a barrier-serialized broadcast).
__global__ __launch_bounds__(256) void fused_gather_softmax_agg(
    const int* __restrict__ data_r,        // [B,N] indices into edge_w
    const int* __restrict__ data_e,        // [B,N] indices into ent_emb
    const int* __restrict__ rel,           // [B]
    const int* __restrict__ pos_id,        // [B]
    const int* __restrict__ neg_id,        // [B]
    const float* __restrict__ ent_emb,     // [500001,128] f32
    const float* __restrict__ edge_w,      // [250501,1]   f32
    const float* __restrict__ rel_emb,     // [500,128]    f32
    float* __restrict__ out)               // [3*B*128]    f32
{
    __shared__ float part[4 * DD];         // [wave][128] partial sums

    const int b    = blockIdx.x;
    const int wave = threadIdx.x >> 6;
    const int lane = threadIdx.x & 63;

    // ---- 1. softmax over the 64 gathered edge weights (one per lane) ----
    const int ridx = data_r[b * NN + lane];
    const int eidx = data_e[b * NN + lane];
    const float wv = edge_w[ridx];

    float m = wv;
#pragma unroll
    for (int off = 32; off; off >>= 1) m = fmaxf(m, __shfl_xor(m, off));
    const float ex = __expf(wv - m);
    float s = ex;
#pragma unroll
    for (int off = 32; off; off >>= 1) s += __shfl_xor(s, off);
    const float w = ex / s;

    // ---- 2. this wave gathers neighbors [wave*16, wave*16+16) ----
    const int rg = lane >> 4;    // 0..3 : row-group
    const int sl = lane & 15;    // 0..15: sub-lane within row-group

    float acc[8];
#pragma unroll
    for (int i = 0; i < 8; ++i) acc[i] = 0.f;

#pragma unroll
    for (int t = 0; t < 4; ++t) {
        const int   n   = wave * 16 + t * 4 + rg;
        const int   idx = __shfl(eidx, n);
        const float wn  = __shfl(w, n);
        const float4* rp = (const float4*)(ent_emb + (size_t)idx * DD);
        const float4 v0 = rp[sl];        // contiguous 256B: dims [4sl, 4sl+4)
        const float4 v1 = rp[sl + 16];   // contiguous 256B: dims [64+4sl, ...)
        acc[0] = fmaf(wn, v0.x, acc[0]); acc[1] = fmaf(wn, v0.y, acc[1]);
        acc[2] = fmaf(wn, v0.z, acc[2]); acc[3] = fmaf(wn, v0.w, acc[3]);
        acc[4] = fmaf(wn, v1.x, acc[4]); acc[5] = fmaf(wn, v1.y, acc[5]);
        acc[6] = fmaf(wn, v1.z, acc[6]); acc[7] = fmaf(wn, v1.w, acc[7]);
    }

    // reduce partials across the 4 row-groups (lanes sl, sl+16, sl+32, sl+48)
#pragma unroll
    for (int i = 0; i < 8; ++i) {
        acc[i] += __shfl_xor(acc[i], 16);
        acc[i] += __shfl_xor(acc[i], 32);
    }

    // lanes 0..15 publish this wave's 128-dim partial to LDS
    if (lane < 16) {
        float* p = part + wave * DD;
        *(float4*)(p + sl * 4)      = make_float4(acc[0], acc[1], acc[2], acc[3]);
        *(float4*)(p + 64 + sl * 4) = make_float4(acc[4], acc[5], acc[6], acc[7]);
    }
    __syncthreads();

    // ---- 3. epilogue ----
    if (wave == 0) {
        // combine 4 wave-partials + rel_emb -> out_t; 2 dims per lane
        const int r = rel[b];
#pragma unroll
        for (int h = 0; h < 2; ++h) {
            const int d = lane + h * 64;
            const float v = part[d] + part[DD + d] + part[2 * DD + d] + part[3 * DD + d];
            out[(size_t)b * DD + d] = v + rel_emb[(size_t)r * DD + d];
        }
    } else if (wave == 1) {
        // lanes 0..31: pos_out copy; lanes 32..63: neg_out copy (512B each)
        const int is_neg = lane >> 5;
        const int id = is_neg ? neg_id[b] : pos_id[b];
        const int q  = lane & 31;
        const float4 v = ((const float4*)(ent_emb + (size_t)id * DD))[q];
        float4* op = (float4*)(out + (size_t)BB * DD * (1 + is_neg) + (size_t)b * DD);
        op[q] = v;
    }
}

extern "C" void kernel_launch(void* const* d_in, const int* in_sizes, int n_in,
                              void* d_out, int out_size, void* d_ws, size_t ws_size,
                              hipStream_t stream) {
    const int* data_r = (const int*)d_in[0];
    const int* data_e = (const int*)d_in[1];
    const int* rel    = (const int*)d_in[2];
    const int* pos_id = (const int*)d_in[3];
    const int* neg_id = (const int*)d_in[4];
    const float* ent_emb = (const float*)d_in[5];
    const float* edge_w  = (const float*)d_in[6];
    const float* rel_emb = (const float*)d_in[7];
    float* out = (float*)d_out;

    dim3 grid(BB);       // one block per batch row
    dim3 block(256);
    fused_gather_softmax_agg<<<grid, block, 0, stream>>>(
        data_r, data_e, rel, pos_id, neg_id, ent_emb, edge_w, rel_emb, out);
}